// Round 1
// baseline (212.818 us; speedup 1.0000x reference)
//
#include <hip/hip_runtime.h>

// HierarchicalEmbedding: e = s_new*lam + t_new*(1-lam)
//   s_new[i] = s[i]                    (i < nwp)
//            = e_prime[cp[i]]          (i >= nwp),  e_prime[j] = s[j]*lam[j] + t[j]*(1-lam[j])
//   t_new[i] = mean_{k<5} t[children_idx[5i+k]]   (i < nwc)
//            = t[i]                                 (i >= nwc)
// Layout: one 64-lane wave per row, float2 per lane (64*8B = 512B = full row of E=128 f32).

constexpr int E = 128;

__global__ void __launch_bounds__(256)
he_kernel(const float* __restrict__ s,
          const float* __restrict__ t,
          const float* __restrict__ lambda_,
          const int* __restrict__ cp,
          const int* __restrict__ children_idx,
          const int* __restrict__ nwc_p,
          const int* __restrict__ nwp_p,
          float* __restrict__ out,
          int n_rows)
{
    const int gid  = blockIdx.x * blockDim.x + threadIdx.x;
    const int row  = gid >> 6;          // one wave per row
    const int lane = gid & 63;
    if (row >= n_rows) return;

    const int nwc = *nwc_p;
    const int nwp = *nwp_p;
    const int col = lane * 2;

    const float lam = lambda_[row];

    // ---- s_new[row] ----
    float2 sv;
    if (row < nwp) {
        sv = *reinterpret_cast<const float2*>(s + (size_t)row * E + col);
    } else {
        const int   j  = cp[row];
        const float lj = lambda_[j];
        const float2 sj = *reinterpret_cast<const float2*>(s + (size_t)j * E + col);
        const float2 tj = *reinterpret_cast<const float2*>(t + (size_t)j * E + col);
        sv.x = sj.x * lj + tj.x * (1.0f - lj);
        sv.y = sj.y * lj + tj.y * (1.0f - lj);
    }

    // ---- t_new[row] ----
    float2 tv;
    if (row < nwc) {
        float2 acc = make_float2(0.0f, 0.0f);
        const int base = row * 5;
        #pragma unroll
        for (int k = 0; k < 5; ++k) {
            const int c = children_idx[base + k];
            const float2 tc = *reinterpret_cast<const float2*>(t + (size_t)c * E + col);
            acc.x += tc.x;
            acc.y += tc.y;
        }
        tv.x = acc.x / 5.0f;
        tv.y = acc.y / 5.0f;
    } else {
        tv = *reinterpret_cast<const float2*>(t + (size_t)row * E + col);
    }

    // ---- e[row] ----
    float2 ev;
    ev.x = sv.x * lam + tv.x * (1.0f - lam);
    ev.y = sv.y * lam + tv.y * (1.0f - lam);
    *reinterpret_cast<float2*>(out + (size_t)row * E + col) = ev;
}

extern "C" void kernel_launch(void* const* d_in, const int* in_sizes, int n_in,
                              void* d_out, int out_size, void* d_ws, size_t ws_size,
                              hipStream_t stream)
{
    const float* s            = (const float*)d_in[0];
    const float* t            = (const float*)d_in[1];
    const float* lambda_      = (const float*)d_in[2];
    const int*   cp           = (const int*)d_in[3];
    const int*   children_idx = (const int*)d_in[4];
    // d_in[5] = seg_ids (regular repeat(arange(nwc),5) -> implicit, unused)
    const int*   nwc_p        = (const int*)d_in[6];
    const int*   nwp_p        = (const int*)d_in[7];

    float* out = (float*)d_out;
    const int n_rows = in_sizes[0] / E;   // (NODE_NUM+1)

    const int threads = 256;              // 4 waves -> 4 rows per block
    const int rows_per_block = threads / 64;
    const int blocks = (n_rows + rows_per_block - 1) / rows_per_block;

    he_kernel<<<blocks, threads, 0, stream>>>(s, t, lambda_, cp, children_idx,
                                              nwc_p, nwp_p, out, n_rows);
}

// Round 2
// 182.944 us; speedup vs baseline: 1.1633x; 1.1633x over previous
//
#include <hip/hip_runtime.h>

// HierarchicalEmbedding: e = s_new*lam + t_new*(1-lam)
//   s_new[i] = s[i]                    (i < nwp)
//            = e_prime[cp[i]]          (i >= nwp),  e_prime[j] = s[j]*lam[j] + t[j]*(1-lam[j])
//   t_new[i] = mean_{k<5} t[children_idx[5i+k]]   (i < nwc)
//            = t[i]                                 (i >= nwc)
//
// Layout: 32 lanes per row, float4 per lane (32*16B = 512B = full row of E=128 f32).
// 16B/lane is the coalescing sweet spot; doubles bytes-in-flight vs float2 version.

constexpr int E = 128;

__global__ void __launch_bounds__(256)
he_kernel(const float* __restrict__ s,
          const float* __restrict__ t,
          const float* __restrict__ lambda_,
          const int* __restrict__ cp,
          const int* __restrict__ children_idx,
          const int* __restrict__ nwc_p,
          const int* __restrict__ nwp_p,
          float* __restrict__ out,
          int n_rows)
{
    const int gid  = blockIdx.x * blockDim.x + threadIdx.x;
    const int row  = gid >> 5;               // 32 threads per row
    const int col  = (gid & 31) << 2;        // float4 column offset
    if (row >= n_rows) return;

    const int nwc = *nwc_p;
    const int nwp = *nwp_p;

    const float lam = lambda_[row];

    // ---- s_new[row] ----
    float4 sv;
    if (row < nwp) {
        sv = *reinterpret_cast<const float4*>(s + (size_t)row * E + col);
    } else {
        const int   j  = cp[row];
        const float lj = lambda_[j];
        const float4 sj = *reinterpret_cast<const float4*>(s + (size_t)j * E + col);
        const float4 tj = *reinterpret_cast<const float4*>(t + (size_t)j * E + col);
        sv.x = sj.x * lj + tj.x * (1.0f - lj);
        sv.y = sj.y * lj + tj.y * (1.0f - lj);
        sv.z = sj.z * lj + tj.z * (1.0f - lj);
        sv.w = sj.w * lj + tj.w * (1.0f - lj);
    }

    // ---- t_new[row] ----
    float4 tv;
    if (row < nwc) {
        const int base = row * 5;
        // independent index loads -> 5 independent gathers in flight
        int c0 = children_idx[base + 0];
        int c1 = children_idx[base + 1];
        int c2 = children_idx[base + 2];
        int c3 = children_idx[base + 3];
        int c4 = children_idx[base + 4];
        const float4 t0 = *reinterpret_cast<const float4*>(t + (size_t)c0 * E + col);
        const float4 t1 = *reinterpret_cast<const float4*>(t + (size_t)c1 * E + col);
        const float4 t2 = *reinterpret_cast<const float4*>(t + (size_t)c2 * E + col);
        const float4 t3 = *reinterpret_cast<const float4*>(t + (size_t)c3 * E + col);
        const float4 t4 = *reinterpret_cast<const float4*>(t + (size_t)c4 * E + col);
        tv.x = (t0.x + t1.x + t2.x + t3.x + t4.x) * 0.2f;
        tv.y = (t0.y + t1.y + t2.y + t3.y + t4.y) * 0.2f;
        tv.z = (t0.z + t1.z + t2.z + t3.z + t4.z) * 0.2f;
        tv.w = (t0.w + t1.w + t2.w + t3.w + t4.w) * 0.2f;
    } else {
        tv = *reinterpret_cast<const float4*>(t + (size_t)row * E + col);
    }

    // ---- e[row] ----
    float4 ev;
    ev.x = sv.x * lam + tv.x * (1.0f - lam);
    ev.y = sv.y * lam + tv.y * (1.0f - lam);
    ev.z = sv.z * lam + tv.z * (1.0f - lam);
    ev.w = sv.w * lam + tv.w * (1.0f - lam);
    *reinterpret_cast<float4*>(out + (size_t)row * E + col) = ev;
}

extern "C" void kernel_launch(void* const* d_in, const int* in_sizes, int n_in,
                              void* d_out, int out_size, void* d_ws, size_t ws_size,
                              hipStream_t stream)
{
    const float* s            = (const float*)d_in[0];
    const float* t            = (const float*)d_in[1];
    const float* lambda_      = (const float*)d_in[2];
    const int*   cp           = (const int*)d_in[3];
    const int*   children_idx = (const int*)d_in[4];
    // d_in[5] = seg_ids (regular repeat(arange(nwc),5) -> implicit, unused)
    const int*   nwc_p        = (const int*)d_in[6];
    const int*   nwp_p        = (const int*)d_in[7];

    float* out = (float*)d_out;
    const int n_rows = in_sizes[0] / E;   // (NODE_NUM+1)

    const int threads = 256;              // 8 rows per block (32 threads/row)
    const int rows_per_block = threads / 32;
    const int blocks = (n_rows + rows_per_block - 1) / rows_per_block;

    he_kernel<<<blocks, threads, 0, stream>>>(s, t, lambda_, cp, children_idx,
                                              nwc_p, nwp_p, out, n_rows);
}